// Round 1
// baseline (80.616 us; speedup 1.0000x reference)
//
#include <hip/hip_runtime.h>

#define T 128              // NUM_STEPS
#define STEPF (1.0f/127.0f)

// ws layout (floats): [0..127] = raw hist sums class 0 (neg), [128..255] = class 1 (pos),
// then 2 uints: counts[0]=neg, counts[1]=pos.

__global__ __launch_bounds__(256) void sim_hist_kernel(
    const float* __restrict__ A, const float* __restrict__ B,
    const int* __restrict__ label, float* __restrict__ ws, int n) {
  __shared__ float hloc[2 * T];
  __shared__ unsigned int cloc[2];
  const int tid = threadIdx.x;
  if (tid < 2 * T) hloc[tid] = 0.0f;
  if (tid < 2) cloc[tid] = 0u;
  __syncthreads();

  const int lane = tid & 31;      // 32-lane group handles one row (32 x float4 = 128 floats)
  const int grp  = tid >> 5;      // 8 groups per 256-thread block
  const long long gstart  = (long long)blockIdx.x * 8 + grp;
  const long long gstride = (long long)gridDim.x * 8;
  const float4* __restrict__ A4 = (const float4*)A;
  const float4* __restrict__ B4 = (const float4*)B;

  for (long long row = gstart; row < n; row += gstride) {
    const float4 va = A4[row * 32 + lane];
    const float4 vb = B4[row * 32 + lane];
    float ab = va.x * vb.x + va.y * vb.y + va.z * vb.z + va.w * vb.w;
    float aa = va.x * va.x + va.y * va.y + va.z * va.z + va.w * va.w;
    float bb = vb.x * vb.x + vb.y * vb.y + vb.z * vb.z + vb.w * vb.w;
#pragma unroll
    for (int off = 16; off > 0; off >>= 1) {   // xor masks <32 stay within the 32-lane group
      ab += __shfl_xor(ab, off);
      aa += __shfl_xor(aa, off);
      bb += __shfl_xor(bb, off);
    }
    if (lane == 0) {
      const int lab = (label[row] == 1) ? 1 : 0;
      const float sim = ab * rsqrtf(aa * bb);
      float s = (sim + 1.0f) * 0.5f;
      s = fminf(fmaxf(s, 0.0f), 1.0f);
      const float idxf = floorf(s / STEPF);    // replicate reference f32 floor(s/STEP)
      const int idx = (int)idxf;
      atomicAdd(&cloc[lab], 1u);
      // bin idx: wb = (-s + t + STEP)/STEP, t = idx*STEP
      const float w0 = (-s + idxf * STEPF + STEPF) / STEPF;
      atomicAdd(&hloc[lab * T + idx], w0);
      // bin idx+1: wa = (s - t + STEP)/STEP, t = (idx+1)*STEP  (dropped if idx+1 == T)
      if (idx + 1 < T) {
        const float w1 = (s - (idxf + 1.0f) * STEPF + STEPF) / STEPF;
        atomicAdd(&hloc[lab * T + idx + 1], w1);
      }
    }
  }
  __syncthreads();

  if (tid < 2 * T) {
    const float v = hloc[tid];
    if (v != 0.0f) atomicAdd(&ws[tid], v);     // zero-skip: only ~2x13 hot bins flush
  }
  if (tid < 2) {
    const unsigned int c = cloc[tid];
    if (c) atomicAdd((unsigned int*)(ws + 2 * T) + tid, c);
  }
}

__global__ void finalize_kernel(const float* __restrict__ ws, float* __restrict__ out) {
  if (threadIdx.x == 0 && blockIdx.x == 0) {
    const unsigned int* cnt = (const unsigned int*)(ws + 2 * T);
    const float negsz = fmaxf((float)cnt[0], 1.0f);
    const float possz = fmaxf((float)cnt[1], 1.0f);
    float cum = 0.0f, loss = 0.0f;
    for (int j = 0; j < T; ++j) {
      const float hp = ws[T + j] / possz;   // class 1 = pos
      const float hn = ws[j] / negsz;       // class 0 = neg
      cum += hp;
      loss += cum * hn;
    }
    out[0] = loss;
  }
}

extern "C" void kernel_launch(void* const* d_in, const int* in_sizes, int n_in,
                              void* d_out, int out_size, void* d_ws, size_t ws_size,
                              hipStream_t stream) {
  const float* A  = (const float*)d_in[0];
  const float* B  = (const float*)d_in[1];
  const int* lab  = (const int*)d_in[2];
  const int n = in_sizes[2];                 // N = 262144 (label count)
  float* ws = (float*)d_ws;

  hipMemsetAsync(d_ws, 0, (2 * T + 2) * sizeof(float), stream);

  const int grid = 2048;                     // 8 blocks/CU * 256 CU; grid-stride over rows
  sim_hist_kernel<<<grid, 256, 0, stream>>>(A, B, lab, ws, n);
  finalize_kernel<<<1, 64, 0, stream>>>(ws, (float*)d_out);
}

// Round 2
// 71.984 us; speedup vs baseline: 1.1199x; 1.1199x over previous
//
#include <hip/hip_runtime.h>

#define T 128              // NUM_STEPS
#define STEPF (1.0f/127.0f)

// ws layout (floats): [0..127] class-0 (neg) raw sums, [128..255] class-1 (pos),
// ws[256] (as uint): count of label==1. neg count = N - pos (labels are {0,1}).

__global__ __launch_bounds__(256) void sim_hist_kernel(
    const float* __restrict__ A, const float* __restrict__ B,
    const int* __restrict__ label, float* __restrict__ ws, int n) {
  __shared__ float hloc[2 * T];
  __shared__ unsigned int ccnt;
  const int tid = threadIdx.x;
  if (tid < 2 * T) hloc[tid] = 0.0f;
  if (tid == 0) ccnt = 0u;
  __syncthreads();

  const int lane4 = tid & 3;       // 4-lane group owns one row: 4 x 8 float4 = 128 floats
  const int grp   = tid >> 2;      // 64 groups per 256-thread block
  const long long gstart  = (long long)blockIdx.x * 64 + grp;
  const long long gstride = (long long)gridDim.x * 64;
  const float4* __restrict__ A4 = (const float4*)A;
  const float4* __restrict__ B4 = (const float4*)B;

  int cnt = 0;
  for (long long row = gstart; row < n; row += gstride) {
    const float4* __restrict__ a = A4 + row * 32 + lane4;
    const float4* __restrict__ b = B4 + row * 32 + lane4;
    float ab = 0.f, aa = 0.f, bb = 0.f;
#pragma unroll
    for (int k = 0; k < 8; ++k) {          // 8 independent float4 pairs per lane
      const float4 va = a[k * 4];
      const float4 vb = b[k * 4];
      ab = fmaf(va.x, vb.x, fmaf(va.y, vb.y, fmaf(va.z, vb.z, fmaf(va.w, vb.w, ab))));
      aa = fmaf(va.x, va.x, fmaf(va.y, va.y, fmaf(va.z, va.z, fmaf(va.w, va.w, aa))));
      bb = fmaf(vb.x, vb.x, fmaf(vb.y, vb.y, fmaf(vb.z, vb.z, fmaf(vb.w, vb.w, bb))));
    }
    // 2-step reduce within the 4-lane group (6 shuffles per wave covering 16 rows)
    ab += __shfl_xor(ab, 1); ab += __shfl_xor(ab, 2);
    aa += __shfl_xor(aa, 1); aa += __shfl_xor(aa, 2);
    bb += __shfl_xor(bb, 1); bb += __shfl_xor(bb, 2);

    if (lane4 == 0) {                      // 16 of 64 lanes active
      const int lab = (label[row] == 1) ? 1 : 0;   // 16 consecutive rows -> coalesced
      cnt += lab;
      const float sim = ab * rsqrtf(aa * bb);
      float s = fminf(fmaxf((sim + 1.0f) * 0.5f, 0.0f), 1.0f);
      const float idxf = floorf(s / STEPF);        // exact reference semantics
      const int idx = (int)idxf;
      const float w0 = (-s + idxf * STEPF + STEPF) / STEPF;
      atomicAdd(&hloc[lab * T + idx], w0);
      if (idx + 1 < T) {
        const float w1 = (s - (idxf + 1.0f) * STEPF + STEPF) / STEPF;
        atomicAdd(&hloc[lab * T + idx + 1], w1);
      }
    }
  }

  // wave-reduce the positive-label count, one LDS atomic per wave
#pragma unroll
  for (int off = 32; off > 0; off >>= 1) cnt += __shfl_xor(cnt, off);
  if ((tid & 63) == 0 && cnt) atomicAdd(&ccnt, (unsigned int)cnt);
  __syncthreads();

  if (tid < 2 * T) {
    const float v = hloc[tid];
    if (v != 0.0f) atomicAdd(&ws[tid], v);   // zero-skip: ~26 hot bins per block
  }
  if (tid == 0 && ccnt) atomicAdd((unsigned int*)(ws + 2 * T), ccnt);
}

__global__ void finalize_kernel(const float* __restrict__ ws, float* __restrict__ out, int n) {
  if (threadIdx.x == 0 && blockIdx.x == 0) {
    const unsigned int cpos = *(const unsigned int*)(ws + 2 * T);
    const float possz = fmaxf((float)cpos, 1.0f);
    const float negsz = fmaxf((float)(n - (int)cpos), 1.0f);
    float cum = 0.0f, loss = 0.0f;
    for (int j = 0; j < T; ++j) {
      const float hp = ws[T + j] / possz;   // class 1 = pos
      const float hn = ws[j] / negsz;       // class 0 = neg
      cum += hp;
      loss += cum * hn;
    }
    out[0] = loss;
  }
}

extern "C" void kernel_launch(void* const* d_in, const int* in_sizes, int n_in,
                              void* d_out, int out_size, void* d_ws, size_t ws_size,
                              hipStream_t stream) {
  const float* A  = (const float*)d_in[0];
  const float* B  = (const float*)d_in[1];
  const int* lab  = (const int*)d_in[2];
  const int n = in_sizes[2];                 // N = 262144
  float* ws = (float*)d_ws;

  hipMemsetAsync(d_ws, 0, (2 * T + 1) * sizeof(float), stream);

  const int grid = 1024;                     // 64 groups/block -> 65536 groups, 4 rows each
  sim_hist_kernel<<<grid, 256, 0, stream>>>(A, B, lab, ws, n);
  finalize_kernel<<<1, 64, 0, stream>>>(ws, (float*)d_out, n);
}

// Round 3
// 55.703 us; speedup vs baseline: 1.4473x; 1.2923x over previous
//
#include <hip/hip_runtime.h>

#define T 128              // NUM_STEPS
#define STEPF (1.0f/127.0f)
#define NCOPY 8            // parallel global histogram copies (contention /8)
#define WSSTRIDE 258       // 256 bins + 1 count + 1 pad, per copy

// ws layout per copy c (floats, base = c*WSSTRIDE):
//   [0..127]   class-0 (neg) raw sums
//   [128..255] class-1 (pos) raw sums
//   [256]      (as uint) count of label==1
// neg count = N - sum(pos counts); labels are {0,1}.

__global__ __launch_bounds__(256) void sim_hist_kernel(
    const float* __restrict__ A, const float* __restrict__ B,
    const int* __restrict__ label, float* __restrict__ ws, int n) {
  __shared__ float hloc[2 * T];
  __shared__ unsigned int ccnt;
  const int tid = threadIdx.x;
  hloc[tid] = 0.0f;                 // 256 threads cover 2*T exactly
  if (tid == 0) ccnt = 0u;
  __syncthreads();

  const int lane4 = tid & 3;        // 4-lane group owns one row: 4 x 8 float4
  const int row   = (blockIdx.x * 256 + tid) >> 2;   // ONE row per group, no loop
  int cnt = 0;

  if (row < n) {
    const float4* __restrict__ a = (const float4*)A + (size_t)row * 32 + lane4;
    const float4* __restrict__ b = (const float4*)B + (size_t)row * 32 + lane4;
    float ab = 0.f, aa = 0.f, bb = 0.f;
#pragma unroll
    for (int k = 0; k < 8; ++k) {   // 16 independent float4 loads, all issued up front
      const float4 va = a[k * 4];
      const float4 vb = b[k * 4];
      ab = fmaf(va.x, vb.x, fmaf(va.y, vb.y, fmaf(va.z, vb.z, fmaf(va.w, vb.w, ab))));
      aa = fmaf(va.x, va.x, fmaf(va.y, va.y, fmaf(va.z, va.z, fmaf(va.w, va.w, aa))));
      bb = fmaf(vb.x, vb.x, fmaf(vb.y, vb.y, fmaf(vb.z, vb.z, fmaf(vb.w, vb.w, bb))));
    }
    ab += __shfl_xor(ab, 1); ab += __shfl_xor(ab, 2);
    aa += __shfl_xor(aa, 1); aa += __shfl_xor(aa, 2);
    bb += __shfl_xor(bb, 1); bb += __shfl_xor(bb, 2);

    if (lane4 == 0) {               // 16 of 64 lanes
      const int lab = (label[row] == 1) ? 1 : 0;   // 16 consecutive rows -> one cacheline
      cnt = lab;
      const float sim = ab * rsqrtf(aa * bb);
      float s = fminf(fmaxf((sim + 1.0f) * 0.5f, 0.0f), 1.0f);
      const float idxf = floorf(s / STEPF);        // exact reference semantics
      const int idx = (int)idxf;
      const float w0 = (-s + idxf * STEPF + STEPF) / STEPF;
      atomicAdd(&hloc[lab * T + idx], w0);
      if (idx + 1 < T) {
        const float w1 = (s - (idxf + 1.0f) * STEPF + STEPF) / STEPF;
        atomicAdd(&hloc[lab * T + idx + 1], w1);
      }
    }
  }

  // wave-reduce positive count; one LDS atomic per wave
#pragma unroll
  for (int off = 32; off > 0; off >>= 1) cnt += __shfl_xor(cnt, off);
  if ((tid & 63) == 0 && cnt) atomicAdd(&ccnt, (unsigned int)cnt);
  __syncthreads();

  float* wsc = ws + (blockIdx.x & (NCOPY - 1)) * WSSTRIDE;
  const float v = hloc[tid];
  if (v != 0.0f) atomicAdd(&wsc[tid], v);          // zero-skip: ~26 hot bins/block
  if (tid == 0 && ccnt) atomicAdd((unsigned int*)(wsc + 2 * T), ccnt);
}

// single-wave parallel finalize: 2 bins per lane, shuffle prefix-scan
__global__ void finalize_kernel(const float* __restrict__ ws, float* __restrict__ out, int n) {
  const int lane = threadIdx.x & 63;
  unsigned int cpos = 0;
  float hp0 = 0.f, hp1 = 0.f, hn0 = 0.f, hn1 = 0.f;
  const int j0 = 2 * lane, j1 = 2 * lane + 1;
#pragma unroll
  for (int c = 0; c < NCOPY; ++c) {
    const float* wsc = ws + c * WSSTRIDE;
    hn0 += wsc[j0];       hn1 += wsc[j1];          // class 0 = neg
    hp0 += wsc[T + j0];   hp1 += wsc[T + j1];      // class 1 = pos
    cpos += ((const unsigned int*)(wsc + 2 * T))[0];
  }
  const float possz = fmaxf((float)cpos, 1.0f);
  const float negsz = fmaxf((float)(n - (int)cpos), 1.0f);
  hp0 /= possz; hp1 /= possz;
  hn0 /= negsz; hn1 /= negsz;

  const float pair = hp0 + hp1;
  float scan = pair;                                // inclusive scan of pair-sums
#pragma unroll
  for (int off = 1; off < 64; off <<= 1) {
    const float u = __shfl_up(scan, off);
    if (lane >= off) scan += u;
  }
  const float excl = scan - pair;
  float part = (excl + hp0) * hn0 + (excl + hp0 + hp1) * hn1;
#pragma unroll
  for (int off = 32; off > 0; off >>= 1) part += __shfl_xor(part, off);
  if (lane == 0) out[0] = part;
}

extern "C" void kernel_launch(void* const* d_in, const int* in_sizes, int n_in,
                              void* d_out, int out_size, void* d_ws, size_t ws_size,
                              hipStream_t stream) {
  const float* A  = (const float*)d_in[0];
  const float* B  = (const float*)d_in[1];
  const int* lab  = (const int*)d_in[2];
  const int n = in_sizes[2];                 // N = 262144
  float* ws = (float*)d_ws;

  hipMemsetAsync(d_ws, 0, NCOPY * WSSTRIDE * sizeof(float), stream);

  const int grid = (n + 63) / 64;            // one 4-lane group per row -> 4096 blocks
  sim_hist_kernel<<<grid, 256, 0, stream>>>(A, B, lab, ws, n);
  finalize_kernel<<<1, 64, 0, stream>>>(ws, (float*)d_out, n);
}